// Round 6
// baseline (587.491 us; speedup 1.0000x reference)
//
#include <hip/hip_runtime.h>
#include <hip/hip_bf16.h>
#include <stdint.h>

#define B_DIM 8192
#define K_DIM 2048
#define N_DIM 2048
#define NSEG 4
#define NT (K_DIM / 64)   // 32 K-tiles of BK=64

typedef short bf16x8 __attribute__((ext_vector_type(8)));   // 8 bf16 (4 VGPRs)
typedef float f32x4 __attribute__((ext_vector_type(4)));
typedef unsigned short ushort8v __attribute__((ext_vector_type(8)));

typedef const __attribute__((address_space(1))) void* gas_ptr;
typedef __attribute__((address_space(3))) void* lds_ptr;

__device__ __forceinline__ unsigned short f2bf(float f) {
  uint32_t u = __float_as_uint(f);
  u += 0x7FFFu + ((u >> 16) & 1u);   // round-to-nearest-even
  return (unsigned short)(u >> 16);
}

// ---------------- W: f32 -> bf16 conversion, 8 elems/thread ----------------
__global__ __launch_bounds__(256)
void convert_kernel(const float* __restrict__ in, unsigned short* __restrict__ out, int n8) {
  int i = blockIdx.x * blockDim.x + threadIdx.x;
  const int stride = gridDim.x * blockDim.x;
  for (; i < n8; i += stride) {
    const float4* p = (const float4*)(in + (size_t)i * 8);
    float4 v0 = p[0];
    float4 v1 = p[1];
    ushort8v r;
    r[0] = f2bf(v0.x); r[1] = f2bf(v0.y); r[2] = f2bf(v0.z); r[3] = f2bf(v0.w);
    r[4] = f2bf(v1.x); r[5] = f2bf(v1.y); r[6] = f2bf(v1.z); r[7] = f2bf(v1.w);
    *(ushort8v*)(out + (size_t)i * 8) = r;
  }
}

// ------ fused: x f32 -> bf16 convert + gates = sigmoid(x @ Wg^T + bg) ------
__global__ __launch_bounds__(256)
void xconv_gates_kernel(const float* __restrict__ x, const float* __restrict__ Wg,
                        const float* __restrict__ bg,
                        unsigned short* __restrict__ xb, float* __restrict__ gates) {
  const int b = blockIdx.x;
  const int tid = threadIdx.x;
  const size_t base = (size_t)b * K_DIM + tid * 8;
  const float4 v0 = *(const float4*)(x + base);
  const float4 v1 = *(const float4*)(x + base + 4);
  ushort8v r;
  r[0] = f2bf(v0.x); r[1] = f2bf(v0.y); r[2] = f2bf(v0.z); r[3] = f2bf(v0.w);
  r[4] = f2bf(v1.x); r[5] = f2bf(v1.y); r[6] = f2bf(v1.z); r[7] = f2bf(v1.w);
  *(ushort8v*)(xb + base) = r;

  float a[4];
#pragma unroll
  for (int s = 0; s < 4; ++s) {
    const float4 w0 = *(const float4*)(Wg + (size_t)s * K_DIM + tid * 8);
    const float4 w1 = *(const float4*)(Wg + (size_t)s * K_DIM + tid * 8 + 4);
    a[s] = v0.x * w0.x + v0.y * w0.y + v0.z * w0.z + v0.w * w0.w
         + v1.x * w1.x + v1.y * w1.y + v1.z * w1.z + v1.w * w1.w;
  }
#pragma unroll
  for (int off = 1; off < 64; off <<= 1) {
#pragma unroll
    for (int s = 0; s < 4; ++s) a[s] += __shfl_xor(a[s], off);
  }
  __shared__ float red[4][4];
  const int wv = tid >> 6;
  if ((tid & 63) == 0) {
#pragma unroll
    for (int s = 0; s < 4; ++s) red[wv][s] = a[s];
  }
  __syncthreads();
  if (tid < 4) {
    float v = red[0][tid] + red[1][tid] + red[2][tid] + red[3][tid] + bg[tid];
    gates[(size_t)b * 4 + tid] = 1.f / (1.f + __expf(-v));
  }
}

// ------------- fused 4-segment GEMM: A direct-from-global, B via LDS --------
// Geometry as R2/R5: block = 256 rows x 64 d x 4 segs, 8 waves = 2M x 4N,
// per-wave 128 rows x 16 d x 4 segs, acc[4][8] f32x4 = 128 VGPR.
// NEW: A-fragments are read straight from global (L1/L2-resident: per-tile CU
// working set 32 KB, shared 4x across wn-waves) via a 4-slot register pipeline
// (prefetch f+2 while MFMA'ing f) -> LDS traffic per tile drops 256->96 KB,
// so the LDS port no longer serializes against the MFMA pipe.
// B: unchanged verified zero-conflict swizzled LDS path, TRIPLE-buffered
// (staged 2 tiles ahead), 1 barrier + counted vmcnt per tile.
__global__ __launch_bounds__(512, 2)
void seg_gemm_kernel(const unsigned short* __restrict__ Xb,
                     const unsigned short* __restrict__ Wb,
                     const float* __restrict__ b_seg,
                     const float* __restrict__ thr,
                     const float* __restrict__ gates,
                     float* __restrict__ out) {
  extern __shared__ __align__(128) char smem[];   // 98304 bytes (3 B-buffers)

  const int tid = threadIdx.x;
  const int lane = tid & 63;
  const int wid = tid >> 6;
  const int wm = wid >> 2;        // 0..1 (m half)
  const int wn = wid & 3;         // 0..3 (d quarter)

  // bijective XCD swizzle: 1024 blocks, 8 XCDs, 128 per XCD
  const int id = blockIdx.x;
  const int swz = (id & 7) * 128 + (id >> 3);
  const int m0 = (swz >> 5) * 256;
  const int n0 = (swz & 31) * 64;

  // ---- B staging constants (verified zero-conflict, R2/R5) ----
  const int row_st = ((tid >> 7) << 4) + ((tid >> 2) & 15);          // + j*64
  const int kb_st  = (((tid >> 6) & 1) << 6) + ((((tid & 3) << 4)) ^ (((tid >> 5) & 1) << 5));
  const int ke_st  = kb_st >> 1;
  const int ldsd   = tid * 16;

  // ---- B read constants (verified zero-conflict, R2/R5) ----
  const int l15 = lane & 15;
  const int kg  = lane >> 4;       // 0..3
  const int aRd = l15 * 64 + ((kg * 16) ^ ((l15 & 8) << 2));
  const int wnB = wn * 2048;

  // ---- A direct-global base: lane reads A[row=m0+wm*128+f*16+l15][kg*8 ..] --
  const unsigned short* aBase = Xb + (size_t)(m0 + wm * 128 + l15) * K_DIM + kg * 8;
#define FROW ((size_t)16 * K_DIM)

  f32x4 acc[NSEG][8];
#pragma unroll
  for (int s = 0; s < NSEG; ++s)
#pragma unroll
    for (int f = 0; f < 8; ++f) acc[s][f] = (f32x4){0.f, 0.f, 0.f, 0.f};

#define STAGE_B(t_, h_, bb_) do {                                                   \
    int e0_ = (h_) * 128 + row_st;                                                  \
    const unsigned short* s0_ = Wb + (size_t)(e0_ >> 6) * (N_DIM * K_DIM) + (size_t)(n0 + (e0_ & 63)) * K_DIM + (t_) * 64 + ke_st; \
    __builtin_amdgcn_global_load_lds((gas_ptr)s0_, (lds_ptr)(smem + (bb_) * 32768 + (h_) * 16384 + ldsd), 16, 0, 0); \
    int e1_ = e0_ + 64;                                                             \
    const unsigned short* s1_ = Wb + (size_t)(e1_ >> 6) * (N_DIM * K_DIM) + (size_t)(n0 + (e1_ & 63)) * K_DIM + (t_) * 64 + ke_st; \
    __builtin_amdgcn_global_load_lds((gas_ptr)s1_, (lds_ptr)(smem + (bb_) * 32768 + (h_) * 16384 + ldsd + 8192), 16, 0, 0); \
  } while (0)

#define MFMA16(a_, b_, c_) __builtin_amdgcn_mfma_f32_16x16x32_bf16(a_, b_, c_, 0, 0, 0)

  // ---- prologue: B(0)->buf0, B(1)->buf1; A frags f0,f1 of tile 0 ----
  STAGE_B(0, 0, 0); STAGE_B(0, 1, 0);
  STAGE_B(1, 0, 1); STAGE_B(1, 1, 1);

  bf16x8 af[4][2];   // 4-slot rotating A pipeline; all indices compile-time
  af[0][0] = *(const bf16x8*)(aBase + 0 * FROW);
  af[0][1] = *(const bf16x8*)(aBase + 0 * FROW + 32);
  af[1][0] = *(const bf16x8*)(aBase + 1 * FROW);
  af[1][1] = *(const bf16x8*)(aBase + 1 * FROW + 32);

  asm volatile("s_waitcnt vmcnt(0)" ::: "memory");
  asm volatile("s_barrier" ::: "memory");

  int bc = 0, bs = 2;   // current / stage-target B buffer (mod 3)
  for (int t = 0; t < NT; ++t) {
    const char* Bb = smem + bc * 32768;
    const unsigned short* aT  = aBase + t * 64;
    const unsigned short* aT1 = aBase + (t + 1) * 64;

    // B fragments for tile t (8 ds_read_b128, zero-conflict)
    bf16x8 bfr[NSEG][2];
#pragma unroll
    for (int s = 0; s < NSEG; ++s) {
      const char* bp = Bb + (s >> 1) * 16384 + (s & 1) * 8192 + wnB + aRd;
      bfr[s][0] = *(const bf16x8*)(bp);
      bfr[s][1] = *(const bf16x8*)(bp + 1024);
    }

#pragma unroll
    for (int f = 0; f < 8; ++f) {
      // prefetch A frag 2 clusters ahead into slot (f+2)&3 (wraps into t+1)
      if (f < 6) {
        af[(f + 2) & 3][0] = *(const bf16x8*)(aT + (f + 2) * FROW);
        af[(f + 2) & 3][1] = *(const bf16x8*)(aT + (f + 2) * FROW + 32);
      } else if (t + 1 < NT) {
        af[(f + 2) & 3][0] = *(const bf16x8*)(aT1 + (f - 6) * FROW);
        af[(f + 2) & 3][1] = *(const bf16x8*)(aT1 + (f - 6) * FROW + 32);
      }
      // spread B staging across the tile
      if (f == 3 && t + 2 < NT) STAGE_B(t + 2, 0, bs);
      if (f == 6 && t + 2 < NT) STAGE_B(t + 2, 1, bs);

      __builtin_amdgcn_s_setprio(1);
#pragma unroll
      for (int s = 0; s < NSEG; ++s)
        acc[s][f] = MFMA16(af[f & 3][0], bfr[s][0], acc[s][f]);
#pragma unroll
      for (int s = 0; s < NSEG; ++s)
        acc[s][f] = MFMA16(af[f & 3][1], bfr[s][1], acc[s][f]);
      __builtin_amdgcn_s_setprio(0);
    }

    // ---- tile tail: counted vmcnt + single barrier ----
    // >=14 VMEM ops issued this tile => vmcnt(6) guarantees B(t+1) (issued
    // last tile) fully landed, while B(t+2)+next A-frags stay in flight.
    if (t < NT - 2)      { asm volatile("s_waitcnt vmcnt(6)" ::: "memory"); }
    else if (t == NT - 2){ asm volatile("s_waitcnt vmcnt(0)" ::: "memory"); }
    asm volatile("s_barrier" ::: "memory");

    bc = (bc == 2) ? 0 : bc + 1;
    bs = (bs == 2) ? 0 : bs + 1;
  }

  // ---------------- epilogue ----------------
  // C/D layout: col = lane&15 (d), row = (lane>>4)*4 + reg (batch)
  const int d = n0 + wn * 16 + l15;
  float bsv[NSEG], thv[NSEG];
#pragma unroll
  for (int s = 0; s < NSEG; ++s) {
    bsv[s] = b_seg[s * N_DIM + d];
    thv[s] = thr[s * N_DIM + d];
  }
#pragma unroll
  for (int f = 0; f < 8; ++f) {
#pragma unroll
    for (int r = 0; r < 4; ++r) {
      const int brow = m0 + wm * 128 + f * 16 + kg * 4 + r;
      const float4 g = *(const float4*)(gates + (size_t)brow * 4);
      const float gv[NSEG] = {g.x, g.y, g.z, g.w};
      float sum = 0.f, prod = 1.f;
#pragma unroll
      for (int s = 0; s < NSEG; ++s) {
        const float seg = acc[s][f][r] + bsv[s];
        const float pl = 1.f / (1.f + __expf(-5.f * (seg - thv[s])));
        const float st = seg * pl * gv[s];
        sum += st;
        prod *= st;
      }
      const float gm = sqrtf(sqrtf(fabsf(prod)));   // |prod|^(1/4)
      out[(size_t)brow * N_DIM + d] = sum + 0.1f * (prod < 0.f ? -gm : gm);
    }
  }
#undef STAGE_B
#undef MFMA16
#undef FROW
}

extern "C" void kernel_launch(void* const* d_in, const int* in_sizes, int n_in,
                              void* d_out, int out_size, void* d_ws, size_t ws_size,
                              hipStream_t stream) {
  const float* x      = (const float*)d_in[0];
  const float* W_seg  = (const float*)d_in[1];
  const float* b_seg  = (const float*)d_in[2];
  const float* thr    = (const float*)d_in[3];
  const float* W_gate = (const float*)d_in[4];
  const float* b_gate = (const float*)d_in[5];
  float* out = (float*)d_out;

  // workspace layout: x_bf16 (32MB) | W_bf16 (32MB) | gates (128KB)
  unsigned short* xb = (unsigned short*)d_ws;
  unsigned short* wb = xb + (size_t)B_DIM * K_DIM;
  float* gates = (float*)(wb + (size_t)NSEG * N_DIM * K_DIM);

  xconv_gates_kernel<<<B_DIM, 256, 0, stream>>>(x, W_gate, b_gate, xb, gates);
  convert_kernel<<<2048, 256, 0, stream>>>(W_seg, wb, NSEG * N_DIM * K_DIM / 8);

  hipFuncSetAttribute((const void*)seg_gemm_kernel,
                      hipFuncAttributeMaxDynamicSharedMemorySize, 98304);
  seg_gemm_kernel<<<1024, 512, 98304, stream>>>(xb, wb, b_seg, thr, gates, out);
}

// Round 7
// 312.109 us; speedup vs baseline: 1.8823x; 1.8823x over previous
//
#include <hip/hip_runtime.h>
#include <hip/hip_bf16.h>
#include <stdint.h>

#define B_DIM 8192
#define K_DIM 2048
#define N_DIM 2048
#define NSEG 4
#define NT (K_DIM / 64)   // 32 K-tiles of BK=64

typedef short bf16x8 __attribute__((ext_vector_type(8)));   // 8 bf16 (4 VGPRs)
typedef float f32x4 __attribute__((ext_vector_type(4)));
typedef unsigned short ushort8v __attribute__((ext_vector_type(8)));

typedef const __attribute__((address_space(1))) void* gas_ptr;
typedef __attribute__((address_space(3))) void* lds_ptr;

__device__ __forceinline__ unsigned short f2bf(float f) {
  uint32_t u = __float_as_uint(f);
  u += 0x7FFFu + ((u >> 16) & 1u);   // round-to-nearest-even
  return (unsigned short)(u >> 16);
}

// ---------------- W: f32 -> bf16 conversion, 8 elems/thread ----------------
__global__ __launch_bounds__(256)
void convert_kernel(const float* __restrict__ in, unsigned short* __restrict__ out, int n8) {
  int i = blockIdx.x * blockDim.x + threadIdx.x;
  const int stride = gridDim.x * blockDim.x;
  for (; i < n8; i += stride) {
    const float4* p = (const float4*)(in + (size_t)i * 8);
    float4 v0 = p[0];
    float4 v1 = p[1];
    ushort8v r;
    r[0] = f2bf(v0.x); r[1] = f2bf(v0.y); r[2] = f2bf(v0.z); r[3] = f2bf(v0.w);
    r[4] = f2bf(v1.x); r[5] = f2bf(v1.y); r[6] = f2bf(v1.z); r[7] = f2bf(v1.w);
    *(ushort8v*)(out + (size_t)i * 8) = r;
  }
}

// ------ fused: x f32 -> bf16 convert + gates = sigmoid(x @ Wg^T + bg) ------
__global__ __launch_bounds__(256)
void xconv_gates_kernel(const float* __restrict__ x, const float* __restrict__ Wg,
                        const float* __restrict__ bg,
                        unsigned short* __restrict__ xb, float* __restrict__ gates) {
  const int b = blockIdx.x;
  const int tid = threadIdx.x;
  const size_t base = (size_t)b * K_DIM + tid * 8;
  const float4 v0 = *(const float4*)(x + base);
  const float4 v1 = *(const float4*)(x + base + 4);
  ushort8v r;
  r[0] = f2bf(v0.x); r[1] = f2bf(v0.y); r[2] = f2bf(v0.z); r[3] = f2bf(v0.w);
  r[4] = f2bf(v1.x); r[5] = f2bf(v1.y); r[6] = f2bf(v1.z); r[7] = f2bf(v1.w);
  *(ushort8v*)(xb + base) = r;

  float a[4];
#pragma unroll
  for (int s = 0; s < 4; ++s) {
    const float4 w0 = *(const float4*)(Wg + (size_t)s * K_DIM + tid * 8);
    const float4 w1 = *(const float4*)(Wg + (size_t)s * K_DIM + tid * 8 + 4);
    a[s] = v0.x * w0.x + v0.y * w0.y + v0.z * w0.z + v0.w * w0.w
         + v1.x * w1.x + v1.y * w1.y + v1.z * w1.z + v1.w * w1.w;
  }
#pragma unroll
  for (int off = 1; off < 64; off <<= 1) {
#pragma unroll
    for (int s = 0; s < 4; ++s) a[s] += __shfl_xor(a[s], off);
  }
  __shared__ float red[4][4];
  const int wv = tid >> 6;
  if ((tid & 63) == 0) {
#pragma unroll
    for (int s = 0; s < 4; ++s) red[wv][s] = a[s];
  }
  __syncthreads();
  if (tid < 4) {
    float v = red[0][tid] + red[1][tid] + red[2][tid] + red[3][tid] + bg[tid];
    gates[(size_t)b * 4 + tid] = 1.f / (1.f + __expf(-v));
  }
}

// ------- fused 4-segment GEMM: counted-lgkm 8-phase pipelined schedule ------
// Geometry = R2/R5 (verified): block 256 rows x 64 d x 4 segs, 8 waves 2Mx4N,
// per-wave 128 rows x 16 d x 4 segs, acc[4][8] f32x4.
// NEW: per-wave software pipeline. Tile = 8 phases of 8 MFMA (m-pair x
// seg-pair). Each phase issues the NEXT phase's 4 ds_reads BEFORE its MFMA
// cluster, then waits a COUNTED lgkmcnt(4) (never 0 mid-tile) + sched_barrier.
// Reads complete under MFMA -> LDS unit and matrix pipe overlap instead of
// alternating CU-wide bursts (the R2/R5 43% serialization).
// LDS 160K: A dbuf 2x32K, B tri-buf 3x32K; gload_lds staging + tile-end
// vmcnt(4) + 1 barrier per tile (all verified in R5).
__global__ __launch_bounds__(512, 2)
void seg_gemm_kernel(const unsigned short* __restrict__ Xb,
                     const unsigned short* __restrict__ Wb,
                     const float* __restrict__ b_seg,
                     const float* __restrict__ thr,
                     const float* __restrict__ gates,
                     float* __restrict__ out) {
  extern __shared__ __align__(128) char smem[];   // 163840 bytes

  const int tid = threadIdx.x;
  const int lane = tid & 63;
  const int wid = tid >> 6;
  const int wm = wid >> 2;        // 0..1 (m half)
  const int wn = wid & 3;         // 0..3 (d quarter)

  // bijective XCD swizzle: 1024 blocks, 8 XCDs, 128 per XCD
  const int id = blockIdx.x;
  const int swz = (id & 7) * 128 + (id >> 3);
  const int m0 = (swz >> 5) * 256;
  const int n0 = (swz & 31) * 64;

  // ---- staging constants (verified zero-conflict, R2/R5) ----
  const int row_st = ((tid >> 7) << 4) + ((tid >> 2) & 15);          // + j*64
  const int kb_st  = (((tid >> 6) & 1) << 6) + ((((tid & 3) << 4)) ^ (((tid >> 5) & 1) << 5));
  const int ke_st  = kb_st >> 1;
  const int ldsd   = tid * 16;

  // ---- read constants (verified zero-conflict, R2/R5) ----
  const int l15 = lane & 15;
  const int kg  = lane >> 4;       // 0..3
  const int aRd = l15 * 64 + ((kg * 16) ^ ((l15 & 8) << 2));
  const int wnB = wn * 2048;

  f32x4 acc[NSEG][8];
#pragma unroll
  for (int s = 0; s < NSEG; ++s)
#pragma unroll
    for (int f = 0; f < 8; ++f) acc[s][f] = (f32x4){0.f, 0.f, 0.f, 0.f};

#define STAGE_A(t_, h_) do { int buf_ = (t_) & 1;                                   \
    const unsigned short* s0_ = Xb + (size_t)(m0 + (h_) * 128 + row_st) * K_DIM + (t_) * 64 + ke_st; \
    __builtin_amdgcn_global_load_lds((gas_ptr)s0_, (lds_ptr)(smem + buf_ * 32768 + (h_) * 16384 + ldsd), 16, 0, 0); \
    const unsigned short* s1_ = Xb + (size_t)(m0 + (h_) * 128 + row_st + 64) * K_DIM + (t_) * 64 + ke_st; \
    __builtin_amdgcn_global_load_lds((gas_ptr)s1_, (lds_ptr)(smem + buf_ * 32768 + (h_) * 16384 + ldsd + 8192), 16, 0, 0); \
  } while (0)

#define STAGE_B(t_, h_, bb_) do {                                                   \
    int e0_ = (h_) * 128 + row_st;                                                  \
    const unsigned short* s0_ = Wb + (size_t)(e0_ >> 6) * (N_DIM * K_DIM) + (size_t)(n0 + (e0_ & 63)) * K_DIM + (t_) * 64 + ke_st; \
    __builtin_amdgcn_global_load_lds((gas_ptr)s0_, (lds_ptr)(smem + 65536 + (bb_) * 32768 + (h_) * 16384 + ldsd), 16, 0, 0); \
    int e1_ = e0_ + 64;                                                             \
    const unsigned short* s1_ = Wb + (size_t)(e1_ >> 6) * (N_DIM * K_DIM) + (size_t)(n0 + (e1_ & 63)) * K_DIM + (t_) * 64 + ke_st; \
    __builtin_amdgcn_global_load_lds((gas_ptr)s1_, (lds_ptr)(smem + 65536 + (bb_) * 32768 + (h_) * 16384 + ldsd + 8192), 16, 0, 0); \
  } while (0)

#define MFMA16(a_, b_, c_) __builtin_amdgcn_mfma_f32_16x16x32_bf16(a_, b_, c_, 0, 0, 0)
#define LD8(p_) (*(const bf16x8*)(p_))

#define WAITL4 do { asm volatile("s_waitcnt lgkmcnt(4)" ::: "memory");              \
                    __builtin_amdgcn_sched_barrier(0); } while (0)
#define WAITL0 do { asm volatile("s_waitcnt lgkmcnt(0)" ::: "memory");              \
                    __builtin_amdgcn_sched_barrier(0); } while (0)

  // 8-MFMA phase cluster: m-pair AP (frags [j][kk]), seg-pair (sa,sb), cols c0,c0+1
#define MM8(AP_, BA_, BB_, sa_, sb_, c0_) do {                                      \
    __builtin_amdgcn_s_setprio(1);                                                  \
    _Pragma("unroll")                                                               \
    for (int kk = 0; kk < 2; ++kk) {                                                \
      acc[sa_][(c0_)]     = MFMA16(AP_[0][kk], BA_[kk], acc[sa_][(c0_)]);           \
      acc[sa_][(c0_) + 1] = MFMA16(AP_[1][kk], BA_[kk], acc[sa_][(c0_) + 1]);       \
      acc[sb_][(c0_)]     = MFMA16(AP_[0][kk], BB_[kk], acc[sb_][(c0_)]);           \
      acc[sb_][(c0_) + 1] = MFMA16(AP_[1][kk], BB_[kk], acc[sb_][(c0_) + 1]);       \
    }                                                                               \
    __builtin_amdgcn_s_setprio(0);                                                  \
  } while (0)

  // ---- prologue: A(0), B(0)->buf0, B(1)->buf1; keep B(1) in flight ----
  STAGE_A(0, 0); STAGE_A(0, 1);
  STAGE_B(0, 0, 0); STAGE_B(0, 1, 0);
  STAGE_B(1, 0, 1); STAGE_B(1, 1, 1);
  asm volatile("s_waitcnt vmcnt(4)" ::: "memory");   // A(0),B(0) landed
  asm volatile("s_barrier" ::: "memory");

  int bc = 0, bs = 2;   // current / stage-target B buffer (mod 3)
  for (int t = 0; t < NT; ++t) {
    const char* Ab = smem + (t & 1) * 32768 + wm * 16384;
    const char* Bb = smem + 65536 + bc * 32768;

    bf16x8 b0[2], b1[2], b2[2], b3[2];
    bf16x8 aP0[2][2], aP1[2][2], aP2[2][2], aP3[2][2];

    // ---- tile-start burst (8 reads): A pair0 + B segs 0,1 ----
    aP0[0][0] = LD8(Ab + 0 * 2048 + aRd);  aP0[0][1] = LD8(Ab + 0 * 2048 + 1024 + aRd);
    aP0[1][0] = LD8(Ab + 1 * 2048 + aRd);  aP0[1][1] = LD8(Ab + 1 * 2048 + 1024 + aRd);
    b0[0] = LD8(Bb + 0 + wnB + aRd);       b0[1] = LD8(Bb + 0 + wnB + 1024 + aRd);
    b1[0] = LD8(Bb + 8192 + wnB + aRd);    b1[1] = LD8(Bb + 8192 + wnB + 1024 + aRd);

    // ph0: issue B segs 2,3; stage A(t+1).h0; MFMA m01 x s01
    b2[0] = LD8(Bb + 16384 + wnB + aRd);   b2[1] = LD8(Bb + 16384 + wnB + 1024 + aRd);
    b3[0] = LD8(Bb + 24576 + wnB + aRd);   b3[1] = LD8(Bb + 24576 + wnB + 1024 + aRd);
    if (t + 1 < NT) STAGE_A(t + 1, 0);
    WAITL4;
    MM8(aP0, b0, b1, 0, 1, 0);

    // ph1: issue A pair1 (frags 2,3); stage A(t+1).h1; MFMA m01 x s23
    aP1[0][0] = LD8(Ab + 2 * 2048 + aRd);  aP1[0][1] = LD8(Ab + 2 * 2048 + 1024 + aRd);
    aP1[1][0] = LD8(Ab + 3 * 2048 + aRd);  aP1[1][1] = LD8(Ab + 3 * 2048 + 1024 + aRd);
    if (t + 1 < NT) STAGE_A(t + 1, 1);
    WAITL4;
    MM8(aP0, b2, b3, 2, 3, 0);

    // ph2: issue A pair2 (frags 4,5); MFMA m23 x s01
    aP2[0][0] = LD8(Ab + 4 * 2048 + aRd);  aP2[0][1] = LD8(Ab + 4 * 2048 + 1024 + aRd);
    aP2[1][0] = LD8(Ab + 5 * 2048 + aRd);  aP2[1][1] = LD8(Ab + 5 * 2048 + 1024 + aRd);
    WAITL4;
    MM8(aP1, b0, b1, 0, 1, 2);

    // ph3: issue A pair3 (frags 6,7); MFMA m23 x s23
    aP3[0][0] = LD8(Ab + 6 * 2048 + aRd);  aP3[0][1] = LD8(Ab + 6 * 2048 + 1024 + aRd);
    aP3[1][0] = LD8(Ab + 7 * 2048 + aRd);  aP3[1][1] = LD8(Ab + 7 * 2048 + 1024 + aRd);
    WAITL4;
    MM8(aP1, b2, b3, 2, 3, 2);

    // ph4: stage B(t+2).h0; MFMA m45 x s01
    if (t + 2 < NT) STAGE_B(t + 2, 0, bs);
    WAITL4;
    MM8(aP2, b0, b1, 0, 1, 4);

    // ph5: stage B(t+2).h1; MFMA m45 x s23
    if (t + 2 < NT) STAGE_B(t + 2, 1, bs);
    WAITL4;
    MM8(aP2, b2, b3, 2, 3, 4);

    // ph6: MFMA m67 x s01 (drain last A reads)
    WAITL0;
    MM8(aP3, b0, b1, 0, 1, 6);

    // ph7: MFMA m67 x s23
    MM8(aP3, b2, b3, 2, 3, 6);

    // ---- tile tail: counted vmcnt + single barrier ----
    if (t < NT - 2)      { asm volatile("s_waitcnt vmcnt(4)" ::: "memory"); }
    else if (t == NT - 2){ asm volatile("s_waitcnt vmcnt(0)" ::: "memory"); }
    asm volatile("s_barrier" ::: "memory");

    bc = (bc == 2) ? 0 : bc + 1;
    bs = (bs == 2) ? 0 : bs + 1;
  }
  asm volatile("s_waitcnt lgkmcnt(0) vmcnt(0)" ::: "memory");

  // ---------------- epilogue ----------------
  // C/D layout: col = lane&15 (d), row = (lane>>4)*4 + reg (batch)
  const int d = n0 + wn * 16 + l15;
  float bsv[NSEG], thv[NSEG];
#pragma unroll
  for (int s = 0; s < NSEG; ++s) {
    bsv[s] = b_seg[s * N_DIM + d];
    thv[s] = thr[s * N_DIM + d];
  }
#pragma unroll
  for (int f = 0; f < 8; ++f) {
#pragma unroll
    for (int r = 0; r < 4; ++r) {
      const int brow = m0 + wm * 128 + f * 16 + kg * 4 + r;
      const float4 g = *(const float4*)(gates + (size_t)brow * 4);
      const float gv[NSEG] = {g.x, g.y, g.z, g.w};
      float sum = 0.f, prod = 1.f;
#pragma unroll
      for (int s = 0; s < NSEG; ++s) {
        const float seg = acc[s][f][r] + bsv[s];
        const float pl = 1.f / (1.f + __expf(-5.f * (seg - thv[s])));
        const float st = seg * pl * gv[s];
        sum += st;
        prod *= st;
      }
      const float gm = sqrtf(sqrtf(fabsf(prod)));   // |prod|^(1/4)
      out[(size_t)brow * N_DIM + d] = sum + 0.1f * (prod < 0.f ? -gm : gm);
    }
  }
#undef STAGE_A
#undef STAGE_B
#undef MFMA16
#undef LD8
#undef WAITL4
#undef WAITL0
#undef MM8
}

extern "C" void kernel_launch(void* const* d_in, const int* in_sizes, int n_in,
                              void* d_out, int out_size, void* d_ws, size_t ws_size,
                              hipStream_t stream) {
  const float* x      = (const float*)d_in[0];
  const float* W_seg  = (const float*)d_in[1];
  const float* b_seg  = (const float*)d_in[2];
  const float* thr    = (const float*)d_in[3];
  const float* W_gate = (const float*)d_in[4];
  const float* b_gate = (const float*)d_in[5];
  float* out = (float*)d_out;

  // workspace layout: x_bf16 (32MB) | W_bf16 (32MB) | gates (128KB)
  unsigned short* xb = (unsigned short*)d_ws;
  unsigned short* wb = xb + (size_t)B_DIM * K_DIM;
  float* gates = (float*)(wb + (size_t)NSEG * N_DIM * K_DIM);

  xconv_gates_kernel<<<B_DIM, 256, 0, stream>>>(x, W_gate, b_gate, xb, gates);
  convert_kernel<<<2048, 256, 0, stream>>>(W_seg, wb, NSEG * N_DIM * K_DIM / 8);

  hipFuncSetAttribute((const void*)seg_gemm_kernel,
                      hipFuncAttributeMaxDynamicSharedMemorySize, 163840);
  seg_gemm_kernel<<<1024, 512, 163840, stream>>>(xb, wb, b_seg, thr, gates, out);
}